// Round 9
// baseline (1625.628 us; speedup 1.0000x reference)
//
#include <hip/hip_runtime.h>

#define HID 256
#define NSTEPS 8

typedef __attribute__((ext_vector_type(4))) float f32x4;
typedef __attribute__((ext_vector_type(8))) short s16x8;

__device__ __forceinline__ unsigned short f2bf(float f) {
  unsigned u = __builtin_bit_cast(unsigned, f);
  u += 0x7fffu + ((u >> 16) & 1u);
  return (unsigned short)(u >> 16);
}
__device__ __forceinline__ float bf2f(unsigned short s) {
  return __builtin_bit_cast(float, ((unsigned)s) << 16);
}

__device__ __forceinline__ f32x4 mfma16(s16x8 a, s16x8 b, f32x4 c) {
  return __builtin_amdgcn_mfma_f32_16x16x32_bf16(a, b, c, 0, 0, 0);
}

// split 8 consecutive fp32 into three bf16 limb fragments (in-register)
__device__ __forceinline__ void split3(const float* p, s16x8& a0, s16x8& a1, s16x8& a2) {
  f32x4 u = *(const f32x4*)p;
  f32x4 v = *(const f32x4*)(p + 4);
  float f[8] = {u[0], u[1], u[2], u[3], v[0], v[1], v[2], v[3]};
#pragma unroll
  for (int j = 0; j < 8; ++j) {
    unsigned short l0 = f2bf(f[j]);
    float r1 = f[j] - bf2f(l0);
    unsigned short l1 = f2bf(r1);
    float r2 = r1 - bf2f(l1);
    a0[j] = (short)l0;
    a1[j] = (short)l1;
    a2[j] = (short)f2bf(r2);
  }
}

// ---------------- weight limb split (row-major, same indexing as source) ----

__global__ void k_limb(const float* __restrict__ in, short* __restrict__ o0,
                       short* __restrict__ o1, short* __restrict__ o2, int n) {
  int i = blockIdx.x * 256 + threadIdx.x;
  if (i < n) {
    float x = in[i];
    unsigned short l0 = f2bf(x);
    float r1 = x - bf2f(l0);
    unsigned short l1 = f2bf(r1);
    o0[i] = (short)l0;
    o1[i] = (short)l1;
    o2[i] = (short)f2bf(r1 - bf2f(l1));
  }
}

// ---------------- CSR by dst (round-1 proven) ----------------

__global__ void k_indeg(const int* __restrict__ dst, int* __restrict__ indeg, int E) {
  int e = blockIdx.x * blockDim.x + threadIdx.x;
  if (e < E) atomicAdd(&indeg[dst[e]], 1);
}

__global__ void k_blocksum(const int* __restrict__ indeg, int* __restrict__ bsum, int N) {
  __shared__ int s[256];
  int i = blockIdx.x * 256 + threadIdx.x;
  s[threadIdx.x] = (i < N) ? indeg[i] : 0;
  __syncthreads();
  for (int st = 128; st > 0; st >>= 1) {
    if (threadIdx.x < st) s[threadIdx.x] += s[threadIdx.x + st];
    __syncthreads();
  }
  if (threadIdx.x == 0) bsum[blockIdx.x] = s[0];
}

__global__ void k_bscan(const int* __restrict__ bsum, int* __restrict__ boff,
                        int NB, int* __restrict__ total) {
  if (threadIdx.x == 0 && blockIdx.x == 0) {
    int a = 0;
    for (int i = 0; i < NB; ++i) { boff[i] = a; a += bsum[i]; }
    *total = a;
  }
}

__global__ void k_scan3(const int* __restrict__ indeg, const int* __restrict__ boff,
                        int* __restrict__ csr_off, int N) {
  __shared__ int s[256];
  int tx = threadIdx.x;
  int i = blockIdx.x * 256 + tx;
  int v = (i < N) ? indeg[i] : 0;
  s[tx] = v;
  __syncthreads();
  for (int st = 1; st < 256; st <<= 1) {
    int t = (tx >= st) ? s[tx - st] : 0;
    __syncthreads();
    s[tx] += t;
    __syncthreads();
  }
  if (i < N) csr_off[i] = boff[blockIdx.x] + s[tx] - v;  // exclusive
}

__global__ void k_fill(const int* __restrict__ src, const int* __restrict__ dst,
                       const int* __restrict__ csr_off, int* __restrict__ cursor,
                       int* __restrict__ csr_src, int E) {
  int e = blockIdx.x * blockDim.x + threadIdx.x;
  if (e < E) {
    int d = dst[e];
    int p = atomicAdd(&cursor[d], 1);
    csr_src[csr_off[d] + p] = src[e];
  }
}

// ---------------- per-step kernels ----------------

// band-compact fp32 gather-sum + 3-limb split epilogue
__global__ void k_aggf(const float* __restrict__ H, int s, int PB,
                       const int* __restrict__ csr_off, const int* __restrict__ csr_src,
                       float* __restrict__ aggF, short* __restrict__ G0,
                       short* __restrict__ G1, short* __restrict__ G2) {
  int c = threadIdx.x;
  for (int r = blockIdx.x; r < PB; r += gridDim.x) {
    int node = s * PB + r;
    int b = csr_off[node], e = csr_off[node + 1];
    float acc = 0.f;
    for (int j = b; j < e; ++j) acc += H[(size_t)csr_src[j] * HID + c];
    size_t o = (size_t)r * HID + c;
    aggF[o] = acc;
    unsigned short l0 = f2bf(acc);
    float r1 = acc - bf2f(l0);
    unsigned short l1 = f2bf(r1);
    G0[o] = (short)l0;
    G1[o] = (short)l1;
    G2[o] = (short)f2bf(r1 - bf2f(l1));
  }
}

// dense with LDS-staged weights (R8-proven, unchanged). Block = 64 x 128.
__global__ __launch_bounds__(256, 2)
void k_dense8(const float* __restrict__ V, const short* __restrict__ dwS,
              const float* __restrict__ db,
              short* __restrict__ A0, short* __restrict__ A1,
              short* __restrict__ A2, int M) {
  __shared__ s16x8 lds[2][24 * 64];  // 24 frags x 64 lanes x 16B, dbuf = 48KB
  const int tid = threadIdx.x;
  const int w = tid >> 6, lane = tid & 63;
  const int lr = lane & 15, lg = lane >> 4;
  const int c0 = blockIdx.x * 128;
  const int m0 = blockIdx.y * 64 + w * 16;
  const float* xrow = V + (size_t)min(m0 + lr, M - 1) * HID;

  const short* sp[6];
  int so[6];
#pragma unroll
  for (int q = 0; q < 6; ++q) {
    int f = w * 6 + q;
    int a = f >> 3, t = f & 7;
    sp[q] = dwS + a * (HID * HID) + (size_t)(c0 + t * 16 + lr) * HID + lg * 8;
    so[q] = f * 64 + lane;
  }

  s16x8 rr[6];
#pragma unroll
  for (int q = 0; q < 6; ++q) rr[q] = *(const s16x8*)(sp[q]);
#pragma unroll
  for (int q = 0; q < 6; ++q) lds[0][so[q]] = rr[q];

  f32x4 acc[8];
#pragma unroll
  for (int t = 0; t < 8; ++t) acc[t] = (f32x4){0.f, 0.f, 0.f, 0.f};

  for (int kc = 0; kc < 8; ++kc) {
    if (kc < 7) {
#pragma unroll
      for (int q = 0; q < 6; ++q) rr[q] = *(const s16x8*)(sp[q] + (kc + 1) * 32);
    }
    __syncthreads();
    const s16x8* buf = lds[kc & 1];
    int kb = kc * 32 + lg * 8;
    s16x8 x0, x1, x2;
    split3(xrow + kb, x0, x1, x2);
#pragma unroll
    for (int t = 0; t < 8; ++t) {
      s16x8 w0f = buf[(0 * 8 + t) * 64 + lane];
      s16x8 w1f = buf[(1 * 8 + t) * 64 + lane];
      s16x8 w2f = buf[(2 * 8 + t) * 64 + lane];
      f32x4 a = acc[t];
      a = mfma16(x0, w0f, a);
      a = mfma16(x0, w1f, a);
      a = mfma16(x1, w0f, a);
      a = mfma16(x1, w1f, a);
      a = mfma16(x0, w2f, a);
      a = mfma16(x2, w0f, a);
      acc[t] = a;
    }
    if (kc < 7) {
#pragma unroll
      for (int q = 0; q < 6; ++q) lds[(kc + 1) & 1][so[q]] = rr[q];
    }
  }

#pragma unroll
  for (int t = 0; t < 8; ++t) {
    int col = c0 + t * 16 + lr;
    float bb = db[col];
#pragma unroll
    for (int r = 0; r < 4; ++r) {
      int row = m0 + lg * 4 + r;
      if (row < M) {
        float v = acc[t][r] + bb;
        unsigned short l0 = f2bf(v);
        float r1 = v - bf2f(l0);
        unsigned short l1 = f2bf(r1);
        size_t o = (size_t)row * HID + col;
        A0[o] = (short)l0;
        A1[o] = (short)l1;
        A2[o] = (short)f2bf(r1 - bf2f(l1));
      }
    }
  }
}

// fused step, c-tile 16: 18 weight frags, 36KB LDS dbuf, ~3 blocks/CU.
// Per-output accumulation chain bit-identical to R8 k_step8 (t folded
// into blockIdx.x; kc order and 6-product order unchanged).
template<bool OUTL>
__global__ __launch_bounds__(256, 3)
void k_step9(const short* __restrict__ X0, const short* __restrict__ X1,
             const short* __restrict__ X2,
             const short* __restrict__ G0, const short* __restrict__ G1,
             const short* __restrict__ G2,
             const float* __restrict__ aggF,
             const short* __restrict__ wSL,
             const float* __restrict__ bi, const float* __restrict__ bh,
             int s, int PB, float* __restrict__ Hf,
             short* __restrict__ L0, short* __restrict__ L1, short* __restrict__ L2) {
  __shared__ s16x8 lds[2][18 * 64];  // 18 frags x 64 lanes x 16B, dbuf = 36KB
  const int tid = threadIdx.x;
  const int w = tid >> 6, lane = tid & 63;
  const int lr = lane & 15, lg = lane >> 4;
  const int c0 = blockIdx.x * 16;
  const int m0w = blockIdx.y * 128 + w * 32;
  const int nb = s * PB;
  const int AS = 768 * HID;

  // frag f = a*3 + g (a: wi0,wi1,wi2,wh0,wh1,wh2); wave w stages f = q*4+w
  const short* sp[5];
  int so[5];
#pragma unroll
  for (int q = 0; q < 5; ++q) {
    int f = q * 4 + w;
    int a = f / 3, g = f - a * 3;
    if (f < 18) {
      sp[q] = wSL + (size_t)a * AS + (size_t)(g * HID + c0 + lr) * HID + lg * 8;
      so[q] = f * 64 + lane;
    } else {
      sp[q] = wSL;
      so[q] = 0;
    }
  }

  s16x8 rr[5];
#pragma unroll
  for (int q = 0; q < 5; ++q)
    if (q * 4 + w < 18) rr[q] = *(const s16x8*)(sp[q]);
#pragma unroll
  for (int q = 0; q < 5; ++q)
    if (q * 4 + w < 18) lds[0][so[q]] = rr[q];

  f32x4 acci[3][2], acch[3][2];  // [gate][rg]
#pragma unroll
  for (int g = 0; g < 3; ++g)
#pragma unroll
    for (int rg = 0; rg < 2; ++rg) {
      acci[g][rg] = (f32x4){0.f, 0.f, 0.f, 0.f};
      acch[g][rg] = (f32x4){0.f, 0.f, 0.f, 0.f};
    }

  int rowA[2];
  rowA[0] = min(m0w + lr, PB - 1);
  rowA[1] = min(m0w + 16 + lr, PB - 1);

  for (int kc = 0; kc < 8; ++kc) {
    if (kc < 7) {
#pragma unroll
      for (int q = 0; q < 5; ++q)
        if (q * 4 + w < 18) rr[q] = *(const s16x8*)(sp[q] + (kc + 1) * 32);
    }
    __syncthreads();
    const s16x8* buf = lds[kc & 1];
    const int kb = kc * 32 + lg * 8;
    s16x8 x0[2], x1[2], x2[2], g0[2], g1[2], g2[2];
#pragma unroll
    for (int rg = 0; rg < 2; ++rg) {
      size_t xb = (size_t)(nb + rowA[rg]) * HID + kb;
      x0[rg] = *(const s16x8*)&X0[xb];
      x1[rg] = *(const s16x8*)&X1[xb];
      x2[rg] = *(const s16x8*)&X2[xb];
      size_t gb = (size_t)rowA[rg] * HID + kb;
      g0[rg] = *(const s16x8*)&G0[gb];
      g1[rg] = *(const s16x8*)&G1[gb];
      g2[rg] = *(const s16x8*)&G2[gb];
    }
#pragma unroll
    for (int g = 0; g < 3; ++g) {
      s16x8 wi0f = buf[(0 * 3 + g) * 64 + lane];
      s16x8 wi1f = buf[(1 * 3 + g) * 64 + lane];
      s16x8 wi2f = buf[(2 * 3 + g) * 64 + lane];
      s16x8 wh0f = buf[(3 * 3 + g) * 64 + lane];
      s16x8 wh1f = buf[(4 * 3 + g) * 64 + lane];
      s16x8 wh2f = buf[(5 * 3 + g) * 64 + lane];
#pragma unroll
      for (int rg = 0; rg < 2; ++rg) {
        f32x4 a = acci[g][rg];
        a = mfma16(x0[rg], wi0f, a);
        a = mfma16(x0[rg], wi1f, a);
        a = mfma16(x1[rg], wi0f, a);
        a = mfma16(x1[rg], wi1f, a);
        a = mfma16(x0[rg], wi2f, a);
        a = mfma16(x2[rg], wi0f, a);
        acci[g][rg] = a;
        f32x4 h = acch[g][rg];
        h = mfma16(g0[rg], wh0f, h);
        h = mfma16(g0[rg], wh1f, h);
        h = mfma16(g1[rg], wh0f, h);
        h = mfma16(g1[rg], wh1f, h);
        h = mfma16(g0[rg], wh2f, h);
        h = mfma16(g2[rg], wh0f, h);
        acch[g][rg] = h;
      }
    }
    if (kc < 7) {
#pragma unroll
      for (int q = 0; q < 5; ++q)
        if (q * 4 + w < 18) lds[(kc + 1) & 1][so[q]] = rr[q];
    }
  }

  {
    int col = c0 + lr;
    float bir = bi[col], biz = bi[HID + col], bin = bi[2 * HID + col];
    float bhr = bh[col], bhz = bh[HID + col], bhn = bh[2 * HID + col];
#pragma unroll
    for (int rg = 0; rg < 2; ++rg) {
#pragma unroll
      for (int r = 0; r < 4; ++r) {
        int row = m0w + rg * 16 + lg * 4 + r;
        if (row < PB) {
          float ir = acci[0][rg][r] + bir;
          float iz = acci[1][rg][r] + biz;
          float in_ = acci[2][rg][r] + bin;
          float hr = acch[0][rg][r] + bhr;
          float hz = acch[1][rg][r] + bhz;
          float hn = acch[2][rg][r] + bhn;
          float rgate = 1.f / (1.f + expf(-(ir + hr)));
          float zg = 1.f / (1.f + expf(-(iz + hz)));
          float ng = tanhf(in_ + rgate * hn);
          float a = aggF[(size_t)row * HID + col];
          float h = (1.f - zg) * ng + zg * a;
          size_t o = (size_t)(nb + row) * HID + col;
          Hf[o] = h;
          if (OUTL) {
            unsigned short l0 = f2bf(h);
            float r1 = h - bf2f(l0);
            unsigned short l1 = f2bf(r1);
            L0[o] = (short)l0;
            L1[o] = (short)l1;
            L2[o] = (short)f2bf(r1 - bf2f(l1));
          }
        }
      }
    }
  }
}

// ---------------- launch ----------------

extern "C" void kernel_launch(void* const* d_in, const int* in_sizes, int n_in,
                              void* d_out, int out_size, void* d_ws, size_t ws_size,
                              hipStream_t stream) {
  const float* V = (const float*)d_in[0];
  const int* E = (const int*)d_in[1];
  const float* dense_w = (const float*)d_in[2];
  const float* dense_b = (const float*)d_in[3];
  const float* w_ih = (const float*)d_in[4];  // [2,768,256]
  const float* w_hh = (const float*)d_in[5];
  const float* b_ih = (const float*)d_in[6];  // [2,768]
  const float* b_hh = (const float*)d_in[7];
  const int N = in_sizes[0] / HID;   // 50000
  const int Ecnt = in_sizes[1] / 2;  // 400000
  const int PB = N / NSTEPS;         // 6250; banded DAG: band = node / PB is a topo order
  const int* src = E;
  const int* dst = E + Ecnt;
  float* out = (float*)d_out;

  const size_t AS = (size_t)768 * HID;  // per limb-array stride (shorts)

  char* p = (char*)d_ws;
  short* A0 = (short*)p;   p += (size_t)N * HID * 2;   // dense out limbs
  short* A1 = (short*)p;   p += (size_t)N * HID * 2;
  short* A2 = (short*)p;   p += (size_t)N * HID * 2;
  float* B = (float*)p;    p += (size_t)N * HID * 4;   // layer-0 hidden fp32
  short* B0 = (short*)p;   p += (size_t)N * HID * 2;   // layer-0 hidden limbs
  short* B1 = (short*)p;   p += (size_t)N * HID * 2;
  short* B2 = (short*)p;   p += (size_t)N * HID * 2;
  float* aggF = (float*)p; p += (size_t)PB * HID * 4;
  short* G0 = (short*)p;   p += (size_t)PB * HID * 2;
  short* G1 = (short*)p;   p += (size_t)PB * HID * 2;
  short* G2 = (short*)p;   p += (size_t)PB * HID * 2;
  short* dwS = (short*)p;  p += (size_t)3 * HID * HID * 2;  // dense limbs 0,1,2
  short* wS = (short*)p;   p += (size_t)2 * 6 * AS * 2;     // [layer][wi0..2,wh0..2]
  int* indeg = (int*)p;    p += (size_t)N * 4;
  int* cursor = (int*)p;   p += (size_t)N * 4;
  int* csr_off = (int*)p;  p += (size_t)(N + 1) * 4;
  int* csr_src = (int*)p;  p += (size_t)Ecnt * 4;
  int* bsum = (int*)p;     p += 256 * 4;
  int* boff = (int*)p;     p += 256 * 4;

  hipMemsetAsync(indeg, 0, (size_t)2 * N * 4, stream);

  const int TB = 256;
  const int egrid = (Ecnt + TB - 1) / TB;
  const int NB = (N + 255) / 256;
  const int wgrid = ((int)AS + 255) / 256;

  // weight limbs; contiguous per-layer grouping [wi0,wi1,wi2,wh0,wh1,wh2]
  k_limb<<<(HID * HID + 255) / 256, TB, 0, stream>>>(
      dense_w, dwS, dwS + HID * HID, dwS + 2 * HID * HID, HID * HID);
  for (int l = 0; l < 2; ++l) {
    k_limb<<<wgrid, TB, 0, stream>>>(w_ih + l * AS, wS + (l * 6 + 0) * AS,
                                     wS + (l * 6 + 1) * AS, wS + (l * 6 + 2) * AS, (int)AS);
    k_limb<<<wgrid, TB, 0, stream>>>(w_hh + l * AS, wS + (l * 6 + 3) * AS,
                                     wS + (l * 6 + 4) * AS, wS + (l * 6 + 5) * AS, (int)AS);
  }

  // dense → A limbs (LDS-staged weights)
  k_dense8<<<dim3(2, (N + 63) / 64), TB, 0, stream>>>(V, dwS, dense_b, A0, A1, A2, N);

  // CSR by dst
  k_indeg<<<egrid, TB, 0, stream>>>(dst, indeg, Ecnt);
  k_blocksum<<<NB, TB, 0, stream>>>(indeg, bsum, N);
  k_bscan<<<1, 1, 0, stream>>>(bsum, boff, NB, csr_off + N);
  k_scan3<<<NB, TB, 0, stream>>>(indeg, boff, csr_off, N);
  k_fill<<<egrid, TB, 0, stream>>>(src, dst, csr_off, cursor, csr_src, Ecnt);

  const dim3 sgrid(HID / 16, (PB + 127) / 128);

  // layer 0: X = A limbs, H = B (+ limbs)
  for (int s = 0; s < NSTEPS; ++s) {
    k_aggf<<<2048, TB, 0, stream>>>(B, s, PB, csr_off, csr_src, aggF, G0, G1, G2);
    k_step9<true><<<sgrid, TB, 0, stream>>>(A0, A1, A2, G0, G1, G2, aggF,
                                            wS, b_ih, b_hh, s, PB, B, B0, B1, B2);
  }
  // layer 1: X = B limbs, H = out fp32
  for (int s = 0; s < NSTEPS; ++s) {
    k_aggf<<<2048, TB, 0, stream>>>(out, s, PB, csr_off, csr_src, aggF, G0, G1, G2);
    k_step9<false><<<sgrid, TB, 0, stream>>>(B0, B1, B2, G0, G1, G2, aggF,
                                             wS + 6 * AS, b_ih + 768, b_hh + 768, s, PB,
                                             out, nullptr, nullptr, nullptr);
  }
}

// Round 10
// 1357.781 us; speedup vs baseline: 1.1973x; 1.1973x over previous
//
#include <hip/hip_runtime.h>

#define HID 256
#define NSTEPS 8

typedef __attribute__((ext_vector_type(4))) float f32x4;
typedef __attribute__((ext_vector_type(8))) short s16x8;
typedef __attribute__((ext_vector_type(4))) short s16x4;

__device__ __forceinline__ unsigned short f2bf(float f) {
  unsigned u = __builtin_bit_cast(unsigned, f);
  u += 0x7fffu + ((u >> 16) & 1u);
  return (unsigned short)(u >> 16);
}
__device__ __forceinline__ float bf2f(unsigned short s) {
  return __builtin_bit_cast(float, ((unsigned)s) << 16);
}

__device__ __forceinline__ f32x4 mfma16(s16x8 a, s16x8 b, f32x4 c) {
  return __builtin_amdgcn_mfma_f32_16x16x32_bf16(a, b, c, 0, 0, 0);
}

// split 8 consecutive fp32 into three bf16 limb fragments (in-register)
__device__ __forceinline__ void split3(const float* p, s16x8& a0, s16x8& a1, s16x8& a2) {
  f32x4 u = *(const f32x4*)p;
  f32x4 v = *(const f32x4*)(p + 4);
  float f[8] = {u[0], u[1], u[2], u[3], v[0], v[1], v[2], v[3]};
#pragma unroll
  for (int j = 0; j < 8; ++j) {
    unsigned short l0 = f2bf(f[j]);
    float r1 = f[j] - bf2f(l0);
    unsigned short l1 = f2bf(r1);
    float r2 = r1 - bf2f(l1);
    a0[j] = (short)l0;
    a1[j] = (short)l1;
    a2[j] = (short)f2bf(r2);
  }
}

// ---------------- weight limb split ----------------

__global__ void k_limb(const float* __restrict__ in, short* __restrict__ o0,
                       short* __restrict__ o1, short* __restrict__ o2, int n) {
  int i = blockIdx.x * 256 + threadIdx.x;
  if (i < n) {
    float x = in[i];
    unsigned short l0 = f2bf(x);
    float r1 = x - bf2f(l0);
    unsigned short l1 = f2bf(r1);
    o0[i] = (short)l0;
    o1[i] = (short)l1;
    o2[i] = (short)f2bf(r1 - bf2f(l1));
  }
}

// ---------------- CSR by dst (round-1 proven) ----------------

__global__ void k_indeg(const int* __restrict__ dst, int* __restrict__ indeg, int E) {
  int e = blockIdx.x * blockDim.x + threadIdx.x;
  if (e < E) atomicAdd(&indeg[dst[e]], 1);
}

__global__ void k_blocksum(const int* __restrict__ indeg, int* __restrict__ bsum, int N) {
  __shared__ int s[256];
  int i = blockIdx.x * 256 + threadIdx.x;
  s[threadIdx.x] = (i < N) ? indeg[i] : 0;
  __syncthreads();
  for (int st = 128; st > 0; st >>= 1) {
    if (threadIdx.x < st) s[threadIdx.x] += s[threadIdx.x + st];
    __syncthreads();
  }
  if (threadIdx.x == 0) bsum[blockIdx.x] = s[0];
}

__global__ void k_bscan(const int* __restrict__ bsum, int* __restrict__ boff,
                        int NB, int* __restrict__ total) {
  if (threadIdx.x == 0 && blockIdx.x == 0) {
    int a = 0;
    for (int i = 0; i < NB; ++i) { boff[i] = a; a += bsum[i]; }
    *total = a;
  }
}

__global__ void k_scan3(const int* __restrict__ indeg, const int* __restrict__ boff,
                        int* __restrict__ csr_off, int N) {
  __shared__ int s[256];
  int tx = threadIdx.x;
  int i = blockIdx.x * 256 + tx;
  int v = (i < N) ? indeg[i] : 0;
  s[tx] = v;
  __syncthreads();
  for (int st = 1; st < 256; st <<= 1) {
    int t = (tx >= st) ? s[tx - st] : 0;
    __syncthreads();
    s[tx] += t;
    __syncthreads();
  }
  if (i < N) csr_off[i] = boff[blockIdx.x] + s[tx] - v;  // exclusive
}

__global__ void k_fill(const int* __restrict__ src, const int* __restrict__ dst,
                       const int* __restrict__ csr_off, int* __restrict__ cursor,
                       int* __restrict__ csr_src, int E) {
  int e = blockIdx.x * blockDim.x + threadIdx.x;
  if (e < E) {
    int d = dst[e];
    int p = atomicAdd(&cursor[d], 1);
    csr_src[csr_off[d] + p] = src[e];
  }
}

// ---------------- per-step kernels ----------------

// dual-layer band gather: z=0 gathers band t for layer 0 (from HA=B),
// z=1 gathers band t-1 for layer 1 (from HB=out). f32x4 per lane,
// 4 rows per block; per-column fp32 add order identical to scalar version.
__global__ void k_aggf2(const float* __restrict__ HA, const float* __restrict__ HB,
                        int t, int PB,
                        const int* __restrict__ csr_off, const int* __restrict__ csr_src,
                        float* __restrict__ aggFA, float* __restrict__ aggFB,
                        short* __restrict__ GA0, short* __restrict__ GA1,
                        short* __restrict__ GA2,
                        short* __restrict__ GB0, short* __restrict__ GB1,
                        short* __restrict__ GB2) {
  const int z = blockIdx.z;
  const int s = t - z;
  if (s < 0 || s >= NSTEPS) return;
  const float* H = z ? HB : HA;
  float* aggF = z ? aggFB : aggFA;
  short* G0 = z ? GB0 : GA0;
  short* G1 = z ? GB1 : GA1;
  short* G2 = z ? GB2 : GA2;

  const int grp = threadIdx.x >> 6, lane = threadIdx.x & 63;
  const int r = blockIdx.x * 4 + grp;
  if (r >= PB) return;
  const int node = s * PB + r;
  const int b = csr_off[node], e = csr_off[node + 1];
  const int c4 = lane * 4;
  f32x4 acc = (f32x4){0.f, 0.f, 0.f, 0.f};
  for (int j = b; j < e; ++j) {
    f32x4 v = *(const f32x4*)&H[(size_t)csr_src[j] * HID + c4];
    acc[0] += v[0]; acc[1] += v[1]; acc[2] += v[2]; acc[3] += v[3];
  }
  size_t o = (size_t)r * HID + c4;
  *(f32x4*)&aggF[o] = acc;
  s16x4 g0, g1, g2;
#pragma unroll
  for (int q = 0; q < 4; ++q) {
    unsigned short l0 = f2bf(acc[q]);
    float r1 = acc[q] - bf2f(l0);
    unsigned short l1 = f2bf(r1);
    g0[q] = (short)l0;
    g1[q] = (short)l1;
    g2[q] = (short)f2bf(r1 - bf2f(l1));
  }
  *(s16x4*)&G0[o] = g0;
  *(s16x4*)&G1[o] = g1;
  *(s16x4*)&G2[o] = g2;
}

// dense with LDS-staged weights (R8-proven, unchanged). Block = 64 x 128.
__global__ __launch_bounds__(256, 2)
void k_dense8(const float* __restrict__ V, const short* __restrict__ dwS,
              const float* __restrict__ db,
              short* __restrict__ A0, short* __restrict__ A1,
              short* __restrict__ A2, int M) {
  __shared__ s16x8 lds[2][24 * 64];  // 48KB dbuf
  const int tid = threadIdx.x;
  const int w = tid >> 6, lane = tid & 63;
  const int lr = lane & 15, lg = lane >> 4;
  const int c0 = blockIdx.x * 128;
  const int m0 = blockIdx.y * 64 + w * 16;
  const float* xrow = V + (size_t)min(m0 + lr, M - 1) * HID;

  const short* sp[6];
  int so[6];
#pragma unroll
  for (int q = 0; q < 6; ++q) {
    int f = w * 6 + q;
    int a = f >> 3, t = f & 7;
    sp[q] = dwS + a * (HID * HID) + (size_t)(c0 + t * 16 + lr) * HID + lg * 8;
    so[q] = f * 64 + lane;
  }

  s16x8 rr[6];
#pragma unroll
  for (int q = 0; q < 6; ++q) rr[q] = *(const s16x8*)(sp[q]);
#pragma unroll
  for (int q = 0; q < 6; ++q) lds[0][so[q]] = rr[q];

  f32x4 acc[8];
#pragma unroll
  for (int t = 0; t < 8; ++t) acc[t] = (f32x4){0.f, 0.f, 0.f, 0.f};

  for (int kc = 0; kc < 8; ++kc) {
    if (kc < 7) {
#pragma unroll
      for (int q = 0; q < 6; ++q) rr[q] = *(const s16x8*)(sp[q] + (kc + 1) * 32);
    }
    __syncthreads();
    const s16x8* buf = lds[kc & 1];
    int kb = kc * 32 + lg * 8;
    s16x8 x0, x1, x2;
    split3(xrow + kb, x0, x1, x2);
#pragma unroll
    for (int t = 0; t < 8; ++t) {
      s16x8 w0f = buf[(0 * 8 + t) * 64 + lane];
      s16x8 w1f = buf[(1 * 8 + t) * 64 + lane];
      s16x8 w2f = buf[(2 * 8 + t) * 64 + lane];
      f32x4 a = acc[t];
      a = mfma16(x0, w0f, a);
      a = mfma16(x0, w1f, a);
      a = mfma16(x1, w0f, a);
      a = mfma16(x1, w1f, a);
      a = mfma16(x0, w2f, a);
      a = mfma16(x2, w0f, a);
      acc[t] = a;
    }
    if (kc < 7) {
#pragma unroll
      for (int q = 0; q < 6; ++q) lds[(kc + 1) & 1][so[q]] = rr[q];
    }
  }

#pragma unroll
  for (int t = 0; t < 8; ++t) {
    int col = c0 + t * 16 + lr;
    float bb = db[col];
#pragma unroll
    for (int r = 0; r < 4; ++r) {
      int row = m0 + lg * 4 + r;
      if (row < M) {
        float v = acc[t][r] + bb;
        unsigned short l0 = f2bf(v);
        float r1 = v - bf2f(l0);
        unsigned short l1 = f2bf(r1);
        size_t o = (size_t)row * HID + col;
        A0[o] = (short)l0;
        A1[o] = (short)l1;
        A2[o] = (short)f2bf(r1 - bf2f(l1));
      }
    }
  }
}

// dual-layer fused step (R8 k_step8 body, math bit-identical; z selects layer):
// z=0: layer-0 step t (X=A limbs, out B fp32 + B limbs)
// z=1: layer-1 step t-1 (X=B limbs, out fp32 `out`)
__global__ __launch_bounds__(256, 2)
void k_step2(const short* __restrict__ A0, const short* __restrict__ A1,
             const short* __restrict__ A2,
             const short* __restrict__ B0, const short* __restrict__ B1,
             const short* __restrict__ B2,
             const short* __restrict__ GA0, const short* __restrict__ GA1,
             const short* __restrict__ GA2,
             const short* __restrict__ GB0, const short* __restrict__ GB1,
             const short* __restrict__ GB2,
             const float* __restrict__ aggFA, const float* __restrict__ aggFB,
             const short* __restrict__ wS,
             const float* __restrict__ b_ih, const float* __restrict__ b_hh,
             int t, int PB, float* __restrict__ Bfp, float* __restrict__ outp) {
  const int z = blockIdx.z;
  const int s = t - z;
  if (s < 0 || s >= NSTEPS) return;

  const short* X0 = z ? B0 : A0;
  const short* X1 = z ? B1 : A1;
  const short* X2 = z ? B2 : A2;
  const short* G0 = z ? GB0 : GA0;
  const short* G1 = z ? GB1 : GA1;
  const short* G2 = z ? GB2 : GA2;
  const float* aggF = z ? aggFB : aggFA;
  const int AS = 768 * HID;
  const short* wSL = wS + (size_t)z * 6 * AS;
  const float* bi = b_ih + z * 768;
  const float* bh = b_hh + z * 768;
  float* Hf = z ? outp : Bfp;
  const bool outl = (z == 0);

  __shared__ s16x8 lds[2][36 * 64];  // 72KB dbuf
  const int tid = threadIdx.x;
  const int w = tid >> 6, lane = tid & 63;
  const int lr = lane & 15, lg = lane >> 4;
  const int c0 = blockIdx.x * 32;
  const int m0w = blockIdx.y * 128 + w * 32;
  const int nb = s * PB;

  const short* sp[9];
  int so[9];
#pragma unroll
  for (int q = 0; q < 9; ++q) {
    int f = w * 9 + q;
    int a = f / 6, gt = f - a * 6, g = gt >> 1, tt = gt & 1;
    sp[q] = wSL + (size_t)a * AS + (size_t)(g * HID + c0 + tt * 16 + lr) * HID + lg * 8;
    so[q] = f * 64 + lane;
  }

  s16x8 rr[9];
#pragma unroll
  for (int q = 0; q < 9; ++q) rr[q] = *(const s16x8*)(sp[q]);
#pragma unroll
  for (int q = 0; q < 9; ++q) lds[0][so[q]] = rr[q];

  f32x4 acci[3][2][2], acch[3][2][2];  // [gate][t][rg]
#pragma unroll
  for (int g = 0; g < 3; ++g)
#pragma unroll
    for (int tt = 0; tt < 2; ++tt)
#pragma unroll
      for (int rg = 0; rg < 2; ++rg) {
        acci[g][tt][rg] = (f32x4){0.f, 0.f, 0.f, 0.f};
        acch[g][tt][rg] = (f32x4){0.f, 0.f, 0.f, 0.f};
      }

  int rowA[2];
  rowA[0] = min(m0w + lr, PB - 1);
  rowA[1] = min(m0w + 16 + lr, PB - 1);

  for (int kc = 0; kc < 8; ++kc) {
    if (kc < 7) {
#pragma unroll
      for (int q = 0; q < 9; ++q) rr[q] = *(const s16x8*)(sp[q] + (kc + 1) * 32);
    }
    __syncthreads();
    const s16x8* buf = lds[kc & 1];
    const int kb = kc * 32 + lg * 8;
    s16x8 x0[2], x1[2], x2[2], g0[2], g1[2], g2[2];
#pragma unroll
    for (int rg = 0; rg < 2; ++rg) {
      size_t xb = (size_t)(nb + rowA[rg]) * HID + kb;
      x0[rg] = *(const s16x8*)&X0[xb];
      x1[rg] = *(const s16x8*)&X1[xb];
      x2[rg] = *(const s16x8*)&X2[xb];
      size_t gb = (size_t)rowA[rg] * HID + kb;
      g0[rg] = *(const s16x8*)&G0[gb];
      g1[rg] = *(const s16x8*)&G1[gb];
      g2[rg] = *(const s16x8*)&G2[gb];
    }
#pragma unroll
    for (int g = 0; g < 3; ++g) {
#pragma unroll
      for (int tt = 0; tt < 2; ++tt) {
        s16x8 wi0f = buf[(0 * 6 + g * 2 + tt) * 64 + lane];
        s16x8 wi1f = buf[(1 * 6 + g * 2 + tt) * 64 + lane];
        s16x8 wi2f = buf[(2 * 6 + g * 2 + tt) * 64 + lane];
        s16x8 wh0f = buf[(3 * 6 + g * 2 + tt) * 64 + lane];
        s16x8 wh1f = buf[(4 * 6 + g * 2 + tt) * 64 + lane];
        s16x8 wh2f = buf[(5 * 6 + g * 2 + tt) * 64 + lane];
#pragma unroll
        for (int rg = 0; rg < 2; ++rg) {
          f32x4 a = acci[g][tt][rg];
          a = mfma16(x0[rg], wi0f, a);
          a = mfma16(x0[rg], wi1f, a);
          a = mfma16(x1[rg], wi0f, a);
          a = mfma16(x1[rg], wi1f, a);
          a = mfma16(x0[rg], wi2f, a);
          a = mfma16(x2[rg], wi0f, a);
          acci[g][tt][rg] = a;
          f32x4 h = acch[g][tt][rg];
          h = mfma16(g0[rg], wh0f, h);
          h = mfma16(g0[rg], wh1f, h);
          h = mfma16(g1[rg], wh0f, h);
          h = mfma16(g1[rg], wh1f, h);
          h = mfma16(g0[rg], wh2f, h);
          h = mfma16(g2[rg], wh0f, h);
          acch[g][tt][rg] = h;
        }
      }
    }
    if (kc < 7) {
#pragma unroll
      for (int q = 0; q < 9; ++q) lds[(kc + 1) & 1][so[q]] = rr[q];
    }
  }

#pragma unroll
  for (int tt = 0; tt < 2; ++tt) {
    int col = c0 + tt * 16 + lr;
    float bir = bi[col], biz = bi[HID + col], bin = bi[2 * HID + col];
    float bhr = bh[col], bhz = bh[HID + col], bhn = bh[2 * HID + col];
#pragma unroll
    for (int rg = 0; rg < 2; ++rg) {
#pragma unroll
      for (int r = 0; r < 4; ++r) {
        int row = m0w + rg * 16 + lg * 4 + r;
        if (row < PB) {
          float ir = acci[0][tt][rg][r] + bir;
          float iz = acci[1][tt][rg][r] + biz;
          float in_ = acci[2][tt][rg][r] + bin;
          float hr = acch[0][tt][rg][r] + bhr;
          float hz = acch[1][tt][rg][r] + bhz;
          float hn = acch[2][tt][rg][r] + bhn;
          float rgate = 1.f / (1.f + expf(-(ir + hr)));
          float zg = 1.f / (1.f + expf(-(iz + hz)));
          float ng = tanhf(in_ + rgate * hn);
          float a = aggF[(size_t)row * HID + col];
          float h = (1.f - zg) * ng + zg * a;
          size_t o = (size_t)(nb + row) * HID + col;
          Hf[o] = h;
          if (outl) {
            unsigned short l0 = f2bf(h);
            float r1 = h - bf2f(l0);
            unsigned short l1 = f2bf(r1);
            ((short*)B0)[o] = (short)l0;
            ((short*)B1)[o] = (short)l1;
            ((short*)B2)[o] = (short)f2bf(r1 - bf2f(l1));
          }
        }
      }
    }
  }
}

// ---------------- launch ----------------

extern "C" void kernel_launch(void* const* d_in, const int* in_sizes, int n_in,
                              void* d_out, int out_size, void* d_ws, size_t ws_size,
                              hipStream_t stream) {
  const float* V = (const float*)d_in[0];
  const int* E = (const int*)d_in[1];
  const float* dense_w = (const float*)d_in[2];
  const float* dense_b = (const float*)d_in[3];
  const float* w_ih = (const float*)d_in[4];  // [2,768,256]
  const float* w_hh = (const float*)d_in[5];
  const float* b_ih = (const float*)d_in[6];  // [2,768]
  const float* b_hh = (const float*)d_in[7];
  const int N = in_sizes[0] / HID;   // 50000
  const int Ecnt = in_sizes[1] / 2;  // 400000
  const int PB = N / NSTEPS;         // 6250; banded DAG: band = node / PB is a topo order
  const int* src = E;
  const int* dst = E + Ecnt;
  float* out = (float*)d_out;

  const size_t AS = (size_t)768 * HID;  // per limb-array stride (shorts)

  char* p = (char*)d_ws;
  short* A0 = (short*)p;    p += (size_t)N * HID * 2;   // dense out limbs
  short* A1 = (short*)p;    p += (size_t)N * HID * 2;
  short* A2 = (short*)p;    p += (size_t)N * HID * 2;
  float* B = (float*)p;     p += (size_t)N * HID * 4;   // layer-0 hidden fp32
  short* B0 = (short*)p;    p += (size_t)N * HID * 2;   // layer-0 hidden limbs
  short* B1 = (short*)p;    p += (size_t)N * HID * 2;
  short* B2 = (short*)p;    p += (size_t)N * HID * 2;
  float* aggFA = (float*)p; p += (size_t)PB * HID * 4;
  float* aggFB = (float*)p; p += (size_t)PB * HID * 4;
  short* GA0 = (short*)p;   p += (size_t)PB * HID * 2;
  short* GA1 = (short*)p;   p += (size_t)PB * HID * 2;
  short* GA2 = (short*)p;   p += (size_t)PB * HID * 2;
  short* GB0 = (short*)p;   p += (size_t)PB * HID * 2;
  short* GB1 = (short*)p;   p += (size_t)PB * HID * 2;
  short* GB2 = (short*)p;   p += (size_t)PB * HID * 2;
  short* dwS = (short*)p;   p += (size_t)3 * HID * HID * 2;  // dense limbs
  short* wS = (short*)p;    p += (size_t)2 * 6 * AS * 2;     // [layer][wi0..2,wh0..2]
  int* indeg = (int*)p;     p += (size_t)N * 4;
  int* cursor = (int*)p;    p += (size_t)N * 4;
  int* csr_off = (int*)p;   p += (size_t)(N + 1) * 4;
  int* csr_src = (int*)p;   p += (size_t)Ecnt * 4;
  int* bsum = (int*)p;      p += 256 * 4;
  int* boff = (int*)p;      p += 256 * 4;

  hipMemsetAsync(indeg, 0, (size_t)2 * N * 4, stream);

  const int TB = 256;
  const int egrid = (Ecnt + TB - 1) / TB;
  const int NB = (N + 255) / 256;
  const int wgrid = ((int)AS + 255) / 256;

  // weight limbs; contiguous per-layer grouping [wi0,wi1,wi2,wh0,wh1,wh2]
  k_limb<<<(HID * HID + 255) / 256, TB, 0, stream>>>(
      dense_w, dwS, dwS + HID * HID, dwS + 2 * HID * HID, HID * HID);
  for (int l = 0; l < 2; ++l) {
    k_limb<<<wgrid, TB, 0, stream>>>(w_ih + l * AS, wS + (l * 6 + 0) * AS,
                                     wS + (l * 6 + 1) * AS, wS + (l * 6 + 2) * AS, (int)AS);
    k_limb<<<wgrid, TB, 0, stream>>>(w_hh + l * AS, wS + (l * 6 + 3) * AS,
                                     wS + (l * 6 + 4) * AS, wS + (l * 6 + 5) * AS, (int)AS);
  }

  // dense → A limbs (LDS-staged weights)
  k_dense8<<<dim3(2, (N + 63) / 64), TB, 0, stream>>>(V, dwS, dense_b, A0, A1, A2, N);

  // CSR by dst
  k_indeg<<<egrid, TB, 0, stream>>>(dst, indeg, Ecnt);
  k_blocksum<<<NB, TB, 0, stream>>>(indeg, bsum, N);
  k_bscan<<<1, 1, 0, stream>>>(bsum, boff, NB, csr_off + N);
  k_scan3<<<NB, TB, 0, stream>>>(indeg, boff, csr_off, N);
  k_fill<<<egrid, TB, 0, stream>>>(src, dst, csr_off, cursor, csr_src, Ecnt);

  // dual-layer software pipeline: t=0..8; z=0 -> layer0 step t, z=1 -> layer1 step t-1
  const dim3 agrid((PB + 3) / 4, 1, 2);
  const dim3 sgrid(HID / 32, (PB + 127) / 128, 2);
  for (int t = 0; t <= NSTEPS; ++t) {
    k_aggf2<<<agrid, TB, 0, stream>>>(B, out, t, PB, csr_off, csr_src,
                                      aggFA, aggFB, GA0, GA1, GA2, GB0, GB1, GB2);
    k_step2<<<sgrid, TB, 0, stream>>>(A0, A1, A2, B0, B1, B2,
                                      GA0, GA1, GA2, GB0, GB1, GB2,
                                      aggFA, aggFB, wS, b_ih, b_hh,
                                      t, PB, B, out);
  }
}

// Round 11
// 1272.367 us; speedup vs baseline: 1.2776x; 1.0671x over previous
//
#include <hip/hip_runtime.h>

#define HID 256
#define NSTEPS 8

typedef __attribute__((ext_vector_type(4))) float f32x4;
typedef __attribute__((ext_vector_type(8))) short s16x8;
typedef __attribute__((ext_vector_type(4))) short s16x4;

__device__ __forceinline__ unsigned short f2bf(float f) {
  unsigned u = __builtin_bit_cast(unsigned, f);
  u += 0x7fffu + ((u >> 16) & 1u);
  return (unsigned short)(u >> 16);
}
__device__ __forceinline__ float bf2f(unsigned short s) {
  return __builtin_bit_cast(float, ((unsigned)s) << 16);
}

__device__ __forceinline__ f32x4 mfma16(s16x8 a, s16x8 b, f32x4 c) {
  return __builtin_amdgcn_mfma_f32_16x16x32_bf16(a, b, c, 0, 0, 0);
}

// split 8 consecutive fp32 into three bf16 limb fragments (in-register)
__device__ __forceinline__ void split3(const float* p, s16x8& a0, s16x8& a1, s16x8& a2) {
  f32x4 u = *(const f32x4*)p;
  f32x4 v = *(const f32x4*)(p + 4);
  float f[8] = {u[0], u[1], u[2], u[3], v[0], v[1], v[2], v[3]};
#pragma unroll
  for (int j = 0; j < 8; ++j) {
    unsigned short l0 = f2bf(f[j]);
    float r1 = f[j] - bf2f(l0);
    unsigned short l1 = f2bf(r1);
    float r2 = r1 - bf2f(l1);
    a0[j] = (short)l0;
    a1[j] = (short)l1;
    a2[j] = (short)f2bf(r2);
  }
}

// ---------------- weight limb split ----------------

__global__ void k_limb(const float* __restrict__ in, short* __restrict__ o0,
                       short* __restrict__ o1, short* __restrict__ o2, int n) {
  int i = blockIdx.x * 256 + threadIdx.x;
  if (i < n) {
    float x = in[i];
    unsigned short l0 = f2bf(x);
    float r1 = x - bf2f(l0);
    unsigned short l1 = f2bf(r1);
    o0[i] = (short)l0;
    o1[i] = (short)l1;
    o2[i] = (short)f2bf(r1 - bf2f(l1));
  }
}

// ---------------- CSR by dst (round-1 proven) ----------------

__global__ void k_indeg(const int* __restrict__ dst, int* __restrict__ indeg, int E) {
  int e = blockIdx.x * blockDim.x + threadIdx.x;
  if (e < E) atomicAdd(&indeg[dst[e]], 1);
}

__global__ void k_blocksum(const int* __restrict__ indeg, int* __restrict__ bsum, int N) {
  __shared__ int s[256];
  int i = blockIdx.x * 256 + threadIdx.x;
  s[threadIdx.x] = (i < N) ? indeg[i] : 0;
  __syncthreads();
  for (int st = 128; st > 0; st >>= 1) {
    if (threadIdx.x < st) s[threadIdx.x] += s[threadIdx.x + st];
    __syncthreads();
  }
  if (threadIdx.x == 0) bsum[blockIdx.x] = s[0];
}

__global__ void k_bscan(const int* __restrict__ bsum, int* __restrict__ boff,
                        int NB, int* __restrict__ total) {
  if (threadIdx.x == 0 && blockIdx.x == 0) {
    int a = 0;
    for (int i = 0; i < NB; ++i) { boff[i] = a; a += bsum[i]; }
    *total = a;
  }
}

__global__ void k_scan3(const int* __restrict__ indeg, const int* __restrict__ boff,
                        int* __restrict__ csr_off, int N) {
  __shared__ int s[256];
  int tx = threadIdx.x;
  int i = blockIdx.x * 256 + tx;
  int v = (i < N) ? indeg[i] : 0;
  s[tx] = v;
  __syncthreads();
  for (int st = 1; st < 256; st <<= 1) {
    int t = (tx >= st) ? s[tx - st] : 0;
    __syncthreads();
    s[tx] += t;
    __syncthreads();
  }
  if (i < N) csr_off[i] = boff[blockIdx.x] + s[tx] - v;  // exclusive
}

__global__ void k_fill(const int* __restrict__ src, const int* __restrict__ dst,
                       const int* __restrict__ csr_off, int* __restrict__ cursor,
                       int* __restrict__ csr_src, int E) {
  int e = blockIdx.x * blockDim.x + threadIdx.x;
  if (e < E) {
    int d = dst[e];
    int p = atomicAdd(&cursor[d], 1);
    csr_src[csr_off[d] + p] = src[e];
  }
}

// ---------------- per-step kernels ----------------

// dual-layer band gather (R10-proven, unchanged)
__global__ void k_aggf2(const float* __restrict__ HA, const float* __restrict__ HB,
                        int t, int PB,
                        const int* __restrict__ csr_off, const int* __restrict__ csr_src,
                        float* __restrict__ aggFA, float* __restrict__ aggFB,
                        short* __restrict__ GA0, short* __restrict__ GA1,
                        short* __restrict__ GA2,
                        short* __restrict__ GB0, short* __restrict__ GB1,
                        short* __restrict__ GB2) {
  const int z = blockIdx.z;
  const int s = t - z;
  if (s < 0 || s >= NSTEPS) return;
  const float* H = z ? HB : HA;
  float* aggF = z ? aggFB : aggFA;
  short* G0 = z ? GB0 : GA0;
  short* G1 = z ? GB1 : GA1;
  short* G2 = z ? GB2 : GA2;

  const int grp = threadIdx.x >> 6, lane = threadIdx.x & 63;
  const int r = blockIdx.x * 4 + grp;
  if (r >= PB) return;
  const int node = s * PB + r;
  const int b = csr_off[node], e = csr_off[node + 1];
  const int c4 = lane * 4;
  f32x4 acc = (f32x4){0.f, 0.f, 0.f, 0.f};
  for (int j = b; j < e; ++j) {
    f32x4 v = *(const f32x4*)&H[(size_t)csr_src[j] * HID + c4];
    acc[0] += v[0]; acc[1] += v[1]; acc[2] += v[2]; acc[3] += v[3];
  }
  size_t o = (size_t)r * HID + c4;
  *(f32x4*)&aggF[o] = acc;
  s16x4 g0, g1, g2;
#pragma unroll
  for (int q = 0; q < 4; ++q) {
    unsigned short l0 = f2bf(acc[q]);
    float r1 = acc[q] - bf2f(l0);
    unsigned short l1 = f2bf(r1);
    g0[q] = (short)l0;
    g1[q] = (short)l1;
    g2[q] = (short)f2bf(r1 - bf2f(l1));
  }
  *(s16x4*)&G0[o] = g0;
  *(s16x4*)&G1[o] = g1;
  *(s16x4*)&G2[o] = g2;
}

// dense with LDS-staged weights (R8-proven, unchanged). Block = 64 x 128.
__global__ __launch_bounds__(256, 2)
void k_dense8(const float* __restrict__ V, const short* __restrict__ dwS,
              const float* __restrict__ db,
              short* __restrict__ A0, short* __restrict__ A1,
              short* __restrict__ A2, int M) {
  __shared__ s16x8 lds[2][24 * 64];  // 48KB dbuf
  const int tid = threadIdx.x;
  const int w = tid >> 6, lane = tid & 63;
  const int lr = lane & 15, lg = lane >> 4;
  const int c0 = blockIdx.x * 128;
  const int m0 = blockIdx.y * 64 + w * 16;
  const float* xrow = V + (size_t)min(m0 + lr, M - 1) * HID;

  const short* sp[6];
  int so[6];
#pragma unroll
  for (int q = 0; q < 6; ++q) {
    int f = w * 6 + q;
    int a = f >> 3, t = f & 7;
    sp[q] = dwS + a * (HID * HID) + (size_t)(c0 + t * 16 + lr) * HID + lg * 8;
    so[q] = f * 64 + lane;
  }

  s16x8 rr[6];
#pragma unroll
  for (int q = 0; q < 6; ++q) rr[q] = *(const s16x8*)(sp[q]);
#pragma unroll
  for (int q = 0; q < 6; ++q) lds[0][so[q]] = rr[q];

  f32x4 acc[8];
#pragma unroll
  for (int t = 0; t < 8; ++t) acc[t] = (f32x4){0.f, 0.f, 0.f, 0.f};

  for (int kc = 0; kc < 8; ++kc) {
    if (kc < 7) {
#pragma unroll
      for (int q = 0; q < 6; ++q) rr[q] = *(const s16x8*)(sp[q] + (kc + 1) * 32);
    }
    __syncthreads();
    const s16x8* buf = lds[kc & 1];
    int kb = kc * 32 + lg * 8;
    s16x8 x0, x1, x2;
    split3(xrow + kb, x0, x1, x2);
#pragma unroll
    for (int t = 0; t < 8; ++t) {
      s16x8 w0f = buf[(0 * 8 + t) * 64 + lane];
      s16x8 w1f = buf[(1 * 8 + t) * 64 + lane];
      s16x8 w2f = buf[(2 * 8 + t) * 64 + lane];
      f32x4 a = acc[t];
      a = mfma16(x0, w0f, a);
      a = mfma16(x0, w1f, a);
      a = mfma16(x1, w0f, a);
      a = mfma16(x1, w1f, a);
      a = mfma16(x0, w2f, a);
      a = mfma16(x2, w0f, a);
      acc[t] = a;
    }
    if (kc < 7) {
#pragma unroll
      for (int q = 0; q < 6; ++q) lds[(kc + 1) & 1][so[q]] = rr[q];
    }
  }

#pragma unroll
  for (int t = 0; t < 8; ++t) {
    int col = c0 + t * 16 + lr;
    float bb = db[col];
#pragma unroll
    for (int r = 0; r < 4; ++r) {
      int row = m0 + lg * 4 + r;
      if (row < M) {
        float v = acc[t][r] + bb;
        unsigned short l0 = f2bf(v);
        float r1 = v - bf2f(l0);
        unsigned short l1 = f2bf(r1);
        size_t o = (size_t)row * HID + col;
        A0[o] = (short)l0;
        A1[o] = (short)l1;
        A2[o] = (short)f2bf(r1 - bf2f(l1));
      }
    }
  }
}

// dual-layer persistent step kernel: c-tile 16, FULL-K weight tile resident
// in LDS (18 frags x 8 kc = 144KB, staged once, no barriers in m-loop).
// 512 threads (8 waves x 32 rows = 256 rows per m-iter), persistent over m.
// Per-output math bit-identical to R9 k_step9 / R10 k_step2
// (same fragment addressing, kc order, product order, epilogue).
__global__ __launch_bounds__(512, 2)
void k_stepP(const short* __restrict__ A0, const short* __restrict__ A1,
             const short* __restrict__ A2,
             const short* __restrict__ B0, const short* __restrict__ B1,
             const short* __restrict__ B2,
             const short* __restrict__ GA0, const short* __restrict__ GA1,
             const short* __restrict__ GA2,
             const short* __restrict__ GB0, const short* __restrict__ GB1,
             const short* __restrict__ GB2,
             const float* __restrict__ aggFA, const float* __restrict__ aggFB,
             const short* __restrict__ wS,
             const float* __restrict__ b_ih, const float* __restrict__ b_hh,
             int t, int PB, float* __restrict__ Bfp, float* __restrict__ outp) {
  const int z = blockIdx.z;
  const int s = t - z;
  if (s < 0 || s >= NSTEPS) return;

  const short* X0 = z ? B0 : A0;
  const short* X1 = z ? B1 : A1;
  const short* X2 = z ? B2 : A2;
  const short* G0 = z ? GB0 : GA0;
  const short* G1 = z ? GB1 : GA1;
  const short* G2 = z ? GB2 : GA2;
  const float* aggF = z ? aggFB : aggFA;
  const int AS = 768 * HID;
  const short* wSL = wS + (size_t)z * 6 * AS;
  const float* bi = b_ih + z * 768;
  const float* bh = b_hh + z * 768;
  float* Hf = z ? outp : Bfp;
  const bool outl = (z == 0);

  __shared__ s16x8 lds[8][18][64];  // [kc][frag][lane], 144KB
  const int tid = threadIdx.x;
  const int w = tid >> 6, lane = tid & 63;
  const int lr = lane & 15, lg = lane >> 4;
  const int c0 = blockIdx.x * 16;
  const int nb = s * PB;

  // stage entire weight tile once: unit u -> frag f = u/8, kc = u%8
  for (int u = w; u < 144; u += 8) {
    int f = u >> 3, kc = u & 7;
    int a = f / 3, g = f - a * 3;
    const short* srcp = wSL + (size_t)a * AS + (size_t)(g * HID + c0 + lr) * HID + kc * 32 + lg * 8;
    lds[kc][f][lane] = *(const s16x8*)srcp;
  }
  __syncthreads();

  for (int m0b = blockIdx.y * 256; m0b < PB; m0b += 256 * gridDim.y) {
    const int m0w = m0b + w * 32;
    int rowA[2];
    rowA[0] = min(m0w + lr, PB - 1);
    rowA[1] = min(m0w + 16 + lr, PB - 1);

    f32x4 acci[3][2], acch[3][2];  // [gate][rg]
#pragma unroll
    for (int g = 0; g < 3; ++g)
#pragma unroll
      for (int rg = 0; rg < 2; ++rg) {
        acci[g][rg] = (f32x4){0.f, 0.f, 0.f, 0.f};
        acch[g][rg] = (f32x4){0.f, 0.f, 0.f, 0.f};
      }

    for (int kc = 0; kc < 8; ++kc) {
      const int kb = kc * 32 + lg * 8;
      s16x8 x0[2], x1[2], x2[2], g0[2], g1[2], g2[2];
#pragma unroll
      for (int rg = 0; rg < 2; ++rg) {
        size_t xb = (size_t)(nb + rowA[rg]) * HID + kb;
        x0[rg] = *(const s16x8*)&X0[xb];
        x1[rg] = *(const s16x8*)&X1[xb];
        x2[rg] = *(const s16x8*)&X2[xb];
        size_t gb = (size_t)rowA[rg] * HID + kb;
        g0[rg] = *(const s16x8*)&G0[gb];
        g1[rg] = *(const s16x8*)&G1[gb];
        g2[rg] = *(const s16x8*)&G2[gb];
      }
#pragma unroll
      for (int g = 0; g < 3; ++g) {
        s16x8 wi0f = lds[kc][0 * 3 + g][lane];
        s16x8 wi1f = lds[kc][1 * 3 + g][lane];
        s16x8 wi2f = lds[kc][2 * 3 + g][lane];
        s16x8 wh0f = lds[kc][3 * 3 + g][lane];
        s16x8 wh1f = lds[kc][4 * 3 + g][lane];
        s16x8 wh2f = lds[kc][5 * 3 + g][lane];
#pragma unroll
        for (int rg = 0; rg < 2; ++rg) {
          f32x4 a = acci[g][rg];
          a = mfma16(x0[rg], wi0f, a);
          a = mfma16(x0[rg], wi1f, a);
          a = mfma16(x1[rg], wi0f, a);
          a = mfma16(x1[rg], wi1f, a);
          a = mfma16(x0[rg], wi2f, a);
          a = mfma16(x2[rg], wi0f, a);
          acci[g][rg] = a;
          f32x4 h = acch[g][rg];
          h = mfma16(g0[rg], wh0f, h);
          h = mfma16(g0[rg], wh1f, h);
          h = mfma16(g1[rg], wh0f, h);
          h = mfma16(g1[rg], wh1f, h);
          h = mfma16(g0[rg], wh2f, h);
          h = mfma16(g2[rg], wh0f, h);
          acch[g][rg] = h;
        }
      }
    }

    {
      int col = c0 + lr;
      float bir = bi[col], biz = bi[HID + col], bin = bi[2 * HID + col];
      float bhr = bh[col], bhz = bh[HID + col], bhn = bh[2 * HID + col];
#pragma unroll
      for (int rg = 0; rg < 2; ++rg) {
#pragma unroll
        for (int r = 0; r < 4; ++r) {
          int row = m0w + rg * 16 + lg * 4 + r;
          if (row < PB) {
            float ir = acci[0][rg][r] + bir;
            float iz = acci[1][rg][r] + biz;
            float in_ = acci[2][rg][r] + bin;
            float hr = acch[0][rg][r] + bhr;
            float hz = acch[1][rg][r] + bhz;
            float hn = acch[2][rg][r] + bhn;
            float rgate = 1.f / (1.f + expf(-(ir + hr)));
            float zg = 1.f / (1.f + expf(-(iz + hz)));
            float ng = tanhf(in_ + rgate * hn);
            float a = aggF[(size_t)row * HID + col];
            float h = (1.f - zg) * ng + zg * a;
            size_t o = (size_t)(nb + row) * HID + col;
            Hf[o] = h;
            if (outl) {
              unsigned short l0 = f2bf(h);
              float r1 = h - bf2f(l0);
              unsigned short l1 = f2bf(r1);
              ((short*)B0)[o] = (short)l0;
              ((short*)B1)[o] = (short)l1;
              ((short*)B2)[o] = (short)f2bf(r1 - bf2f(l1));
            }
          }
        }
      }
    }
  }
}

// ---------------- launch ----------------

extern "C" void kernel_launch(void* const* d_in, const int* in_sizes, int n_in,
                              void* d_out, int out_size, void* d_ws, size_t ws_size,
                              hipStream_t stream) {
  const float* V = (const float*)d_in[0];
  const int* E = (const int*)d_in[1];
  const float* dense_w = (const float*)d_in[2];
  const float* dense_b = (const float*)d_in[3];
  const float* w_ih = (const float*)d_in[4];  // [2,768,256]
  const float* w_hh = (const float*)d_in[5];
  const float* b_ih = (const float*)d_in[6];  // [2,768]
  const float* b_hh = (const float*)d_in[7];
  const int N = in_sizes[0] / HID;   // 50000
  const int Ecnt = in_sizes[1] / 2;  // 400000
  const int PB = N / NSTEPS;         // 6250; banded DAG: band = node / PB is a topo order
  const int* src = E;
  const int* dst = E + Ecnt;
  float* out = (float*)d_out;

  const size_t AS = (size_t)768 * HID;  // per limb-array stride (shorts)

  char* p = (char*)d_ws;
  short* A0 = (short*)p;    p += (size_t)N * HID * 2;   // dense out limbs
  short* A1 = (short*)p;    p += (size_t)N * HID * 2;
  short* A2 = (short*)p;    p += (size_t)N * HID * 2;
  float* B = (float*)p;     p += (size_t)N * HID * 4;   // layer-0 hidden fp32
  short* B0 = (short*)p;    p += (size_t)N * HID * 2;   // layer-0 hidden limbs
  short* B1 = (short*)p;    p += (size_t)N * HID * 2;
  short* B2 = (short*)p;    p += (size_t)N * HID * 2;
  float* aggFA = (float*)p; p += (size_t)PB * HID * 4;
  float* aggFB = (float*)p; p += (size_t)PB * HID * 4;
  short* GA0 = (short*)p;   p += (size_t)PB * HID * 2;
  short* GA1 = (short*)p;   p += (size_t)PB * HID * 2;
  short* GA2 = (short*)p;   p += (size_t)PB * HID * 2;
  short* GB0 = (short*)p;   p += (size_t)PB * HID * 2;
  short* GB1 = (short*)p;   p += (size_t)PB * HID * 2;
  short* GB2 = (short*)p;   p += (size_t)PB * HID * 2;
  short* dwS = (short*)p;   p += (size_t)3 * HID * HID * 2;  // dense limbs
  short* wS = (short*)p;    p += (size_t)2 * 6 * AS * 2;     // [layer][wi0..2,wh0..2]
  int* indeg = (int*)p;     p += (size_t)N * 4;
  int* cursor = (int*)p;    p += (size_t)N * 4;
  int* csr_off = (int*)p;   p += (size_t)(N + 1) * 4;
  int* csr_src = (int*)p;   p += (size_t)Ecnt * 4;
  int* bsum = (int*)p;      p += 256 * 4;
  int* boff = (int*)p;      p += 256 * 4;

  hipMemsetAsync(indeg, 0, (size_t)2 * N * 4, stream);

  const int TB = 256;
  const int egrid = (Ecnt + TB - 1) / TB;
  const int NB = (N + 255) / 256;
  const int wgrid = ((int)AS + 255) / 256;

  // weight limbs; contiguous per-layer grouping [wi0,wi1,wi2,wh0,wh1,wh2]
  k_limb<<<(HID * HID + 255) / 256, TB, 0, stream>>>(
      dense_w, dwS, dwS + HID * HID, dwS + 2 * HID * HID, HID * HID);
  for (int l = 0; l < 2; ++l) {
    k_limb<<<wgrid, TB, 0, stream>>>(w_ih + l * AS, wS + (l * 6 + 0) * AS,
                                     wS + (l * 6 + 1) * AS, wS + (l * 6 + 2) * AS, (int)AS);
    k_limb<<<wgrid, TB, 0, stream>>>(w_hh + l * AS, wS + (l * 6 + 3) * AS,
                                     wS + (l * 6 + 4) * AS, wS + (l * 6 + 5) * AS, (int)AS);
  }

  // dense → A limbs (LDS-staged weights)
  k_dense8<<<dim3(2, (N + 63) / 64), TB, 0, stream>>>(V, dwS, dense_b, A0, A1, A2, N);

  // CSR by dst
  k_indeg<<<egrid, TB, 0, stream>>>(dst, indeg, Ecnt);
  k_blocksum<<<NB, TB, 0, stream>>>(indeg, bsum, N);
  k_bscan<<<1, 1, 0, stream>>>(bsum, boff, NB, csr_off + N);
  k_scan3<<<NB, TB, 0, stream>>>(indeg, boff, csr_off, N);
  k_fill<<<egrid, TB, 0, stream>>>(src, dst, csr_off, cursor, csr_src, Ecnt);

  // dual-layer software pipeline: t=0..8; z=0 -> layer0 step t, z=1 -> layer1 step t-1
  const dim3 agrid((PB + 3) / 4, 1, 2);
  const dim3 sgrid(HID / 16, 8, 2);
  for (int t = 0; t <= NSTEPS; ++t) {
    k_aggf2<<<agrid, TB, 0, stream>>>(B, out, t, PB, csr_off, csr_src,
                                      aggFA, aggFB, GA0, GA1, GA2, GB0, GB1, GB2);
    k_stepP<<<sgrid, 512, 0, stream>>>(A0, A1, A2, B0, B1, B2,
                                       GA0, GA1, GA2, GB0, GB1, GB2,
                                       aggFA, aggFB, wS, b_ih, b_hh,
                                       t, PB, B, out);
  }
}

// Round 12
// 1221.344 us; speedup vs baseline: 1.3310x; 1.0418x over previous
//
#include <hip/hip_runtime.h>

#define HID 256
#define NSTEPS 8

typedef __attribute__((ext_vector_type(4))) float f32x4;
typedef __attribute__((ext_vector_type(8))) short s16x8;
typedef __attribute__((ext_vector_type(4))) short s16x4;

__device__ __forceinline__ unsigned short f2bf(float f) {
  unsigned u = __builtin_bit_cast(unsigned, f);
  u += 0x7fffu + ((u >> 16) & 1u);
  return (unsigned short)(u >> 16);
}
__device__ __forceinline__ float bf2f(unsigned short s) {
  return __builtin_bit_cast(float, ((unsigned)s) << 16);
}

__device__ __forceinline__ f32x4 mfma16(s16x8 a, s16x8 b, f32x4 c) {
  return __builtin_amdgcn_mfma_f32_16x16x32_bf16(a, b, c, 0, 0, 0);
}

// split 8 consecutive fp32 into three bf16 limb fragments (in-register)
__device__ __forceinline__ void split3(const float* p, s16x8& a0, s16x8& a1, s16x8& a2) {
  f32x4 u = *(const f32x4*)p;
  f32x4 v = *(const f32x4*)(p + 4);
  float f[8] = {u[0], u[1], u[2], u[3], v[0], v[1], v[2], v[3]};
#pragma unroll
  for (int j = 0; j < 8; ++j) {
    unsigned short l0 = f2bf(f[j]);
    float r1 = f[j] - bf2f(l0);
    unsigned short l1 = f2bf(r1);
    float r2 = r1 - bf2f(l1);
    a0[j] = (short)l0;
    a1[j] = (short)l1;
    a2[j] = (short)f2bf(r2);
  }
}

// ---------------- weight limb split ----------------

__global__ void k_limb(const float* __restrict__ in, short* __restrict__ o0,
                       short* __restrict__ o1, short* __restrict__ o2, int n) {
  int i = blockIdx.x * 256 + threadIdx.x;
  if (i < n) {
    float x = in[i];
    unsigned short l0 = f2bf(x);
    float r1 = x - bf2f(l0);
    unsigned short l1 = f2bf(r1);
    o0[i] = (short)l0;
    o1[i] = (short)l1;
    o2[i] = (short)f2bf(r1 - bf2f(l1));
  }
}

// ---------------- CSR by dst (round-1 proven) ----------------

__global__ void k_indeg(const int* __restrict__ dst, int* __restrict__ indeg, int E) {
  int e = blockIdx.x * blockDim.x + threadIdx.x;
  if (e < E) atomicAdd(&indeg[dst[e]], 1);
}

__global__ void k_blocksum(const int* __restrict__ indeg, int* __restrict__ bsum, int N) {
  __shared__ int s[256];
  int i = blockIdx.x * 256 + threadIdx.x;
  s[threadIdx.x] = (i < N) ? indeg[i] : 0;
  __syncthreads();
  for (int st = 128; st > 0; st >>= 1) {
    if (threadIdx.x < st) s[threadIdx.x] += s[threadIdx.x + st];
    __syncthreads();
  }
  if (threadIdx.x == 0) bsum[blockIdx.x] = s[0];
}

__global__ void k_bscan(const int* __restrict__ bsum, int* __restrict__ boff,
                        int NB, int* __restrict__ total) {
  if (threadIdx.x == 0 && blockIdx.x == 0) {
    int a = 0;
    for (int i = 0; i < NB; ++i) { boff[i] = a; a += bsum[i]; }
    *total = a;
  }
}

__global__ void k_scan3(const int* __restrict__ indeg, const int* __restrict__ boff,
                        int* __restrict__ csr_off, int N) {
  __shared__ int s[256];
  int tx = threadIdx.x;
  int i = blockIdx.x * 256 + tx;
  int v = (i < N) ? indeg[i] : 0;
  s[tx] = v;
  __syncthreads();
  for (int st = 1; st < 256; st <<= 1) {
    int t = (tx >= st) ? s[tx - st] : 0;
    __syncthreads();
    s[tx] += t;
    __syncthreads();
  }
  if (i < N) csr_off[i] = boff[blockIdx.x] + s[tx] - v;  // exclusive
}

__global__ void k_fill(const int* __restrict__ src, const int* __restrict__ dst,
                       const int* __restrict__ csr_off, int* __restrict__ cursor,
                       int* __restrict__ csr_src, int E) {
  int e = blockIdx.x * blockDim.x + threadIdx.x;
  if (e < E) {
    int d = dst[e];
    int p = atomicAdd(&cursor[d], 1);
    csr_src[csr_off[d] + p] = src[e];
  }
}

// ---------------- per-step kernels ----------------

// dual-layer band gather (R10-proven, unchanged)
__global__ void k_aggf2(const float* __restrict__ HA, const float* __restrict__ HB,
                        int t, int PB,
                        const int* __restrict__ csr_off, const int* __restrict__ csr_src,
                        float* __restrict__ aggFA, float* __restrict__ aggFB,
                        short* __restrict__ GA0, short* __restrict__ GA1,
                        short* __restrict__ GA2,
                        short* __restrict__ GB0, short* __restrict__ GB1,
                        short* __restrict__ GB2) {
  const int z = blockIdx.z;
  const int s = t - z;
  if (s < 0 || s >= NSTEPS) return;
  const float* H = z ? HB : HA;
  float* aggF = z ? aggFB : aggFA;
  short* G0 = z ? GB0 : GA0;
  short* G1 = z ? GB1 : GA1;
  short* G2 = z ? GB2 : GA2;

  const int grp = threadIdx.x >> 6, lane = threadIdx.x & 63;
  const int r = blockIdx.x * 4 + grp;
  if (r >= PB) return;
  const int node = s * PB + r;
  const int b = csr_off[node], e = csr_off[node + 1];
  const int c4 = lane * 4;
  f32x4 acc = (f32x4){0.f, 0.f, 0.f, 0.f};
  for (int j = b; j < e; ++j) {
    f32x4 v = *(const f32x4*)&H[(size_t)csr_src[j] * HID + c4];
    acc[0] += v[0]; acc[1] += v[1]; acc[2] += v[2]; acc[3] += v[3];
  }
  size_t o = (size_t)r * HID + c4;
  *(f32x4*)&aggF[o] = acc;
  s16x4 g0, g1, g2;
#pragma unroll
  for (int q = 0; q < 4; ++q) {
    unsigned short l0 = f2bf(acc[q]);
    float r1 = acc[q] - bf2f(l0);
    unsigned short l1 = f2bf(r1);
    g0[q] = (short)l0;
    g1[q] = (short)l1;
    g2[q] = (short)f2bf(r1 - bf2f(l1));
  }
  *(s16x4*)&G0[o] = g0;
  *(s16x4*)&G1[o] = g1;
  *(s16x4*)&G2[o] = g2;
}

// dense with LDS-staged weights (R8-proven, unchanged). Block = 64 x 128.
__global__ __launch_bounds__(256, 2)
void k_dense8(const float* __restrict__ V, const short* __restrict__ dwS,
              const float* __restrict__ db,
              short* __restrict__ A0, short* __restrict__ A1,
              short* __restrict__ A2, int M) {
  __shared__ s16x8 lds[2][24 * 64];  // 48KB dbuf
  const int tid = threadIdx.x;
  const int w = tid >> 6, lane = tid & 63;
  const int lr = lane & 15, lg = lane >> 4;
  const int c0 = blockIdx.x * 128;
  const int m0 = blockIdx.y * 64 + w * 16;
  const float* xrow = V + (size_t)min(m0 + lr, M - 1) * HID;

  const short* sp[6];
  int so[6];
#pragma unroll
  for (int q = 0; q < 6; ++q) {
    int f = w * 6 + q;
    int a = f >> 3, t = f & 7;
    sp[q] = dwS + a * (HID * HID) + (size_t)(c0 + t * 16 + lr) * HID + lg * 8;
    so[q] = f * 64 + lane;
  }

  s16x8 rr[6];
#pragma unroll
  for (int q = 0; q < 6; ++q) rr[q] = *(const s16x8*)(sp[q]);
#pragma unroll
  for (int q = 0; q < 6; ++q) lds[0][so[q]] = rr[q];

  f32x4 acc[8];
#pragma unroll
  for (int t = 0; t < 8; ++t) acc[t] = (f32x4){0.f, 0.f, 0.f, 0.f};

  for (int kc = 0; kc < 8; ++kc) {
    if (kc < 7) {
#pragma unroll
      for (int q = 0; q < 6; ++q) rr[q] = *(const s16x8*)(sp[q] + (kc + 1) * 32);
    }
    __syncthreads();
    const s16x8* buf = lds[kc & 1];
    int kb = kc * 32 + lg * 8;
    s16x8 x0, x1, x2;
    split3(xrow + kb, x0, x1, x2);
#pragma unroll
    for (int t = 0; t < 8; ++t) {
      s16x8 w0f = buf[(0 * 8 + t) * 64 + lane];
      s16x8 w1f = buf[(1 * 8 + t) * 64 + lane];
      s16x8 w2f = buf[(2 * 8 + t) * 64 + lane];
      f32x4 a = acc[t];
      a = mfma16(x0, w0f, a);
      a = mfma16(x0, w1f, a);
      a = mfma16(x1, w0f, a);
      a = mfma16(x1, w1f, a);
      a = mfma16(x0, w2f, a);
      a = mfma16(x2, w0f, a);
      acc[t] = a;
    }
    if (kc < 7) {
#pragma unroll
      for (int q = 0; q < 6; ++q) lds[(kc + 1) & 1][so[q]] = rr[q];
    }
  }

#pragma unroll
  for (int t = 0; t < 8; ++t) {
    int col = c0 + t * 16 + lr;
    float bb = db[col];
#pragma unroll
    for (int r = 0; r < 4; ++r) {
      int row = m0 + lg * 4 + r;
      if (row < M) {
        float v = acc[t][r] + bb;
        unsigned short l0 = f2bf(v);
        float r1 = v - bf2f(l0);
        unsigned short l1 = f2bf(r1);
        size_t o = (size_t)row * HID + col;
        A0[o] = (short)l0;
        A1[o] = (short)l1;
        A2[o] = (short)f2bf(r1 - bf2f(l1));
      }
    }
  }
}

// dual-layer persistent step kernel with XCD-aware block swizzle.
// 1-D grid of 256 blocks; decode so the 16 c-tiles of one (ym,z) group get
// linear ids congruent mod 8 -> same XCD -> shared operand reads in its L2.
// Per-block math bit-identical to R11 k_stepP.
__global__ __launch_bounds__(512, 2)
void k_stepP(const short* __restrict__ A0, const short* __restrict__ A1,
             const short* __restrict__ A2,
             const short* __restrict__ B0, const short* __restrict__ B1,
             const short* __restrict__ B2,
             const short* __restrict__ GA0, const short* __restrict__ GA1,
             const short* __restrict__ GA2,
             const short* __restrict__ GB0, const short* __restrict__ GB1,
             const short* __restrict__ GB2,
             const float* __restrict__ aggFA, const float* __restrict__ aggFB,
             const short* __restrict__ wS,
             const float* __restrict__ b_ih, const float* __restrict__ b_hh,
             int t, int PB, float* __restrict__ Bfp, float* __restrict__ outp) {
  // XCD-aware decode: ids {g%8 + 8k} -> XCD g%8 (linear id % 8 round-robin)
  const int L = blockIdx.x;
  const int xcd = L & 7;
  const int slot = L >> 3;          // 0..31
  const int g = xcd + 8 * (slot >> 4);  // group 0..15
  const int cblk = slot & 15;       // c-tile 0..15
  const int ym = g >> 1;            // 0..7
  const int z = g & 1;

  const int s = t - z;
  if (s < 0 || s >= NSTEPS) return;

  const short* X0 = z ? B0 : A0;
  const short* X1 = z ? B1 : A1;
  const short* X2 = z ? B2 : A2;
  const short* G0 = z ? GB0 : GA0;
  const short* G1 = z ? GB1 : GA1;
  const short* G2 = z ? GB2 : GA2;
  const float* aggF = z ? aggFB : aggFA;
  const int AS = 768 * HID;
  const short* wSL = wS + (size_t)z * 6 * AS;
  const float* bi = b_ih + z * 768;
  const float* bh = b_hh + z * 768;
  float* Hf = z ? outp : Bfp;
  const bool outl = (z == 0);

  __shared__ s16x8 lds[8][18][64];  // [kc][frag][lane], 144KB
  const int tid = threadIdx.x;
  const int w = tid >> 6, lane = tid & 63;
  const int lr = lane & 15, lg = lane >> 4;
  const int c0 = cblk * 16;
  const int nb = s * PB;

  // stage entire weight tile once: unit u -> frag f = u/8, kc = u%8
  for (int u = w; u < 144; u += 8) {
    int f = u >> 3, kc = u & 7;
    int a = f / 3, gg = f - a * 3;
    const short* srcp = wSL + (size_t)a * AS + (size_t)(gg * HID + c0 + lr) * HID + kc * 32 + lg * 8;
    lds[kc][f][lane] = *(const s16x8*)srcp;
  }
  __syncthreads();

  for (int m0b = ym * 256; m0b < PB; m0b += 2048) {
    const int m0w = m0b + w * 32;
    int rowA[2];
    rowA[0] = min(m0w + lr, PB - 1);
    rowA[1] = min(m0w + 16 + lr, PB - 1);

    f32x4 acci[3][2], acch[3][2];  // [gate][rg]
#pragma unroll
    for (int gg = 0; gg < 3; ++gg)
#pragma unroll
      for (int rg = 0; rg < 2; ++rg) {
        acci[gg][rg] = (f32x4){0.f, 0.f, 0.f, 0.f};
        acch[gg][rg] = (f32x4){0.f, 0.f, 0.f, 0.f};
      }

    for (int kc = 0; kc < 8; ++kc) {
      const int kb = kc * 32 + lg * 8;
      s16x8 x0[2], x1[2], x2[2], g0[2], g1[2], g2[2];
#pragma unroll
      for (int rg = 0; rg < 2; ++rg) {
        size_t xb = (size_t)(nb + rowA[rg]) * HID + kb;
        x0[rg] = *(const s16x8*)&X0[xb];
        x1[rg] = *(const s16x8*)&X1[xb];
        x2[rg] = *(const s16x8*)&X2[xb];
        size_t gb = (size_t)rowA[rg] * HID + kb;
        g0[rg] = *(const s16x8*)&G0[gb];
        g1[rg] = *(const s16x8*)&G1[gb];
        g2[rg] = *(const s16x8*)&G2[gb];
      }
#pragma unroll
      for (int gg = 0; gg < 3; ++gg) {
        s16x8 wi0f = lds[kc][0 * 3 + gg][lane];
        s16x8 wi1f = lds[kc][1 * 3 + gg][lane];
        s16x8 wi2f = lds[kc][2 * 3 + gg][lane];
        s16x8 wh0f = lds[kc][3 * 3 + gg][lane];
        s16x8 wh1f = lds[kc][4 * 3 + gg][lane];
        s16x8 wh2f = lds[kc][5 * 3 + gg][lane];
#pragma unroll
        for (int rg = 0; rg < 2; ++rg) {
          f32x4 a = acci[gg][rg];
          a = mfma16(x0[rg], wi0f, a);
          a = mfma16(x0[rg], wi1f, a);
          a = mfma16(x1[rg], wi0f, a);
          a = mfma16(x1[rg], wi1f, a);
          a = mfma16(x0[rg], wi2f, a);
          a = mfma16(x2[rg], wi0f, a);
          acci[gg][rg] = a;
          f32x4 h = acch[gg][rg];
          h = mfma16(g0[rg], wh0f, h);
          h = mfma16(g0[rg], wh1f, h);
          h = mfma16(g1[rg], wh0f, h);
          h = mfma16(g1[rg], wh1f, h);
          h = mfma16(g0[rg], wh2f, h);
          h = mfma16(g2[rg], wh0f, h);
          acch[gg][rg] = h;
        }
      }
    }

    {
      int col = c0 + lr;
      float bir = bi[col], biz = bi[HID + col], bin = bi[2 * HID + col];
      float bhr = bh[col], bhz = bh[HID + col], bhn = bh[2 * HID + col];
#pragma unroll
      for (int rg = 0; rg < 2; ++rg) {
#pragma unroll
        for (int r = 0; r < 4; ++r) {
          int row = m0w + rg * 16 + lg * 4 + r;
          if (row < PB) {
            float ir = acci[0][rg][r] + bir;
            float iz = acci[1][rg][r] + biz;
            float in_ = acci[2][rg][r] + bin;
            float hr = acch[0][rg][r] + bhr;
            float hz = acch[1][rg][r] + bhz;
            float hn = acch[2][rg][r] + bhn;
            float rgate = 1.f / (1.f + expf(-(ir + hr)));
            float zg = 1.f / (1.f + expf(-(iz + hz)));
            float ng = tanhf(in_ + rgate * hn);
            float a = aggF[(size_t)row * HID + col];
            float h = (1.f - zg) * ng + zg * a;
            size_t o = (size_t)(nb + row) * HID + col;
            Hf[o] = h;
            if (outl) {
              unsigned short l0 = f2bf(h);
              float r1 = h - bf2f(l0);
              unsigned short l1 = f2bf(r1);
              ((short*)B0)[o] = (short)l0;
              ((short*)B1)[o] = (short)l1;
              ((short*)B2)[o] = (short)f2bf(r1 - bf2f(l1));
            }
          }
        }
      }
    }
  }
}

// ---------------- launch ----------------

extern "C" void kernel_launch(void* const* d_in, const int* in_sizes, int n_in,
                              void* d_out, int out_size, void* d_ws, size_t ws_size,
                              hipStream_t stream) {
  const float* V = (const float*)d_in[0];
  const int* E = (const int*)d_in[1];
  const float* dense_w = (const float*)d_in[2];
  const float* dense_b = (const float*)d_in[3];
  const float* w_ih = (const float*)d_in[4];  // [2,768,256]
  const float* w_hh = (const float*)d_in[5];
  const float* b_ih = (const float*)d_in[6];  // [2,768]
  const float* b_hh = (const float*)d_in[7];
  const int N = in_sizes[0] / HID;   // 50000
  const int Ecnt = in_sizes[1] / 2;  // 400000
  const int PB = N / NSTEPS;         // 6250; banded DAG: band = node / PB is a topo order
  const int* src = E;
  const int* dst = E + Ecnt;
  float* out = (float*)d_out;

  const size_t AS = (size_t)768 * HID;  // per limb-array stride (shorts)

  char* p = (char*)d_ws;
  short* A0 = (short*)p;    p += (size_t)N * HID * 2;   // dense out limbs
  short* A1 = (short*)p;    p += (size_t)N * HID * 2;
  short* A2 = (short*)p;    p += (size_t)N * HID * 2;
  float* B = (float*)p;     p += (size_t)N * HID * 4;   // layer-0 hidden fp32
  short* B0 = (short*)p;    p += (size_t)N * HID * 2;   // layer-0 hidden limbs
  short* B1 = (short*)p;    p += (size_t)N * HID * 2;
  short* B2 = (short*)p;    p += (size_t)N * HID * 2;
  float* aggFA = (float*)p; p += (size_t)PB * HID * 4;
  float* aggFB = (float*)p; p += (size_t)PB * HID * 4;
  short* GA0 = (short*)p;   p += (size_t)PB * HID * 2;
  short* GA1 = (short*)p;   p += (size_t)PB * HID * 2;
  short* GA2 = (short*)p;   p += (size_t)PB * HID * 2;
  short* GB0 = (short*)p;   p += (size_t)PB * HID * 2;
  short* GB1 = (short*)p;   p += (size_t)PB * HID * 2;
  short* GB2 = (short*)p;   p += (size_t)PB * HID * 2;
  short* dwS = (short*)p;   p += (size_t)3 * HID * HID * 2;  // dense limbs
  short* wS = (short*)p;    p += (size_t)2 * 6 * AS * 2;     // [layer][wi0..2,wh0..2]
  int* indeg = (int*)p;     p += (size_t)N * 4;
  int* cursor = (int*)p;    p += (size_t)N * 4;
  int* csr_off = (int*)p;   p += (size_t)(N + 1) * 4;
  int* csr_src = (int*)p;   p += (size_t)Ecnt * 4;
  int* bsum = (int*)p;      p += 256 * 4;
  int* boff = (int*)p;      p += 256 * 4;

  hipMemsetAsync(indeg, 0, (size_t)2 * N * 4, stream);

  const int TB = 256;
  const int egrid = (Ecnt + TB - 1) / TB;
  const int NB = (N + 255) / 256;
  const int wgrid = ((int)AS + 255) / 256;

  // weight limbs; contiguous per-layer grouping [wi0,wi1,wi2,wh0,wh1,wh2]
  k_limb<<<(HID * HID + 255) / 256, TB, 0, stream>>>(
      dense_w, dwS, dwS + HID * HID, dwS + 2 * HID * HID, HID * HID);
  for (int l = 0; l < 2; ++l) {
    k_limb<<<wgrid, TB, 0, stream>>>(w_ih + l * AS, wS + (l * 6 + 0) * AS,
                                     wS + (l * 6 + 1) * AS, wS + (l * 6 + 2) * AS, (int)AS);
    k_limb<<<wgrid, TB, 0, stream>>>(w_hh + l * AS, wS + (l * 6 + 3) * AS,
                                     wS + (l * 6 + 4) * AS, wS + (l * 6 + 5) * AS, (int)AS);
  }

  // dense → A limbs (LDS-staged weights)
  k_dense8<<<dim3(2, (N + 63) / 64), TB, 0, stream>>>(V, dwS, dense_b, A0, A1, A2, N);

  // CSR by dst
  k_indeg<<<egrid, TB, 0, stream>>>(dst, indeg, Ecnt);
  k_blocksum<<<NB, TB, 0, stream>>>(indeg, bsum, N);
  k_bscan<<<1, 1, 0, stream>>>(bsum, boff, NB, csr_off + N);
  k_scan3<<<NB, TB, 0, stream>>>(indeg, boff, csr_off, N);
  k_fill<<<egrid, TB, 0, stream>>>(src, dst, csr_off, cursor, csr_src, Ecnt);

  // dual-layer software pipeline: t=0..8; z=0 -> layer0 step t, z=1 -> layer1 step t-1
  const dim3 agrid((PB + 3) / 4, 1, 2);
  for (int t = 0; t <= NSTEPS; ++t) {
    k_aggf2<<<agrid, TB, 0, stream>>>(B, out, t, PB, csr_off, csr_src,
                                      aggFA, aggFB, GA0, GA1, GA2, GB0, GB1, GB2);
    k_stepP<<<256, 512, 0, stream>>>(A0, A1, A2, B0, B1, B2,
                                     GA0, GA1, GA2, GB0, GB1, GB2,
                                     aggFA, aggFB, wS, b_ih, b_hh,
                                     t, PB, B, out);
  }
}